// Round 1
// baseline (4108.012 us; speedup 1.0000x reference)
//
#include <hip/hip_runtime.h>
#include <hip/hip_bf16.h>

#define D_IN   100
#define D_HID  256
#define D_OUT  40
#define BN_EPS 1e-5f

// ---------------------------------------------------------------- init: agg1 = x
__global__ void init_copy_f4(const float* __restrict__ src, float* __restrict__ dst, int total4) {
    int stride = gridDim.x * blockDim.x;
    for (int i = blockIdx.x * blockDim.x + threadIdx.x; i < total4; i += stride)
        ((float4*)dst)[i] = ((const float4*)src)[i];
}

// ---------------------------------------------------------------- scatter layer 1: agg1[dst] += x[src]  (100 feats = 25 f4)
__global__ void scatter1(const float* __restrict__ x, const int* __restrict__ src,
                         const int* __restrict__ dst, float* __restrict__ agg, int E) {
    int total = E * 25;
    int stride = gridDim.x * blockDim.x;
    for (int w = blockIdx.x * blockDim.x + threadIdx.x; w < total; w += stride) {
        int e = w / 25;
        int c = w - e * 25;
        int s = src[e], d = dst[e];
        float4 v = *(const float4*)(x + (size_t)s * D_IN + c * 4);
        float* p = agg + (size_t)d * D_IN + c * 4;
        atomicAdd(p + 0, v.x); atomicAdd(p + 1, v.y);
        atomicAdd(p + 2, v.z); atomicAdd(p + 3, v.w);
    }
}

// ---------------------------------------------------------------- GEMM1: h_pre = agg1[N,100] @ W1[100,256] + b1
// block 256 thr, tile 64 rows x 64 cols, BK=32 (K=100 padded w/ zeros)
__global__ __launch_bounds__(256) void gemm1(const float* __restrict__ A, const float* __restrict__ W,
                                             const float* __restrict__ bias, float* __restrict__ C, int N) {
    __shared__ float At[64][33];
    __shared__ float Bt[32][64];
    int r0 = blockIdx.x * 64;
    int c0 = blockIdx.y * 64;
    int tid = threadIdx.x;
    int row = tid & 63;
    int cg  = tid >> 6;          // 0..3, 16 cols each; uniform per wave -> Bt broadcast
    float acc[16];
    #pragma unroll
    for (int j = 0; j < 16; ++j) acc[j] = 0.f;

    for (int k0 = 0; k0 < D_IN; k0 += 32) {
        #pragma unroll
        for (int i = 0; i < 2; ++i) {            // A tile: 64x32 = 512 f4
            int idx = i * 256 + tid;
            int r = idx >> 3, kk4 = idx & 7;
            int k = k0 + kk4 * 4;
            float4 v = make_float4(0.f, 0.f, 0.f, 0.f);
            if (r0 + r < N && k < D_IN)
                v = *(const float4*)(A + (size_t)(r0 + r) * D_IN + k);
            At[r][kk4 * 4 + 0] = v.x; At[r][kk4 * 4 + 1] = v.y;
            At[r][kk4 * 4 + 2] = v.z; At[r][kk4 * 4 + 3] = v.w;
        }
        #pragma unroll
        for (int i = 0; i < 2; ++i) {            // B tile: 32x64 = 512 f4
            int idx = i * 256 + tid;
            int kk = idx >> 4, c4 = idx & 15;
            int k = k0 + kk;
            float4 v = make_float4(0.f, 0.f, 0.f, 0.f);
            if (k < D_IN)
                v = *(const float4*)(W + (size_t)k * D_HID + c0 + c4 * 4);
            Bt[kk][c4 * 4 + 0] = v.x; Bt[kk][c4 * 4 + 1] = v.y;
            Bt[kk][c4 * 4 + 2] = v.z; Bt[kk][c4 * 4 + 3] = v.w;
        }
        __syncthreads();
        #pragma unroll
        for (int kk = 0; kk < 32; ++kk) {
            float a = At[row][kk];
            #pragma unroll
            for (int j = 0; j < 16; ++j)
                acc[j] += a * Bt[kk][cg * 16 + j];
        }
        __syncthreads();
    }
    if (r0 + row < N) {
        float* out = C + (size_t)(r0 + row) * D_HID + c0 + cg * 16;
        #pragma unroll
        for (int j = 0; j < 16; ++j)
            out[j] = acc[j] + bias[c0 + cg * 16 + j];
    }
}

// ---------------------------------------------------------------- column stats for [N,256]
__global__ __launch_bounds__(256) void stats_hid(const float* __restrict__ H, int N,
                                                 float* __restrict__ sum, float* __restrict__ sumsq) {
    int c = threadIdx.x;
    float s = 0.f, q = 0.f;
    for (int r = blockIdx.x; r < N; r += gridDim.x) {
        float v = H[(size_t)r * D_HID + c];
        s += v; q += v * v;
    }
    atomicAdd(&sum[c], s);
    atomicAdd(&sumsq[c], q);
}

// ---------------------------------------------------------------- column stats for [N,40]
__global__ __launch_bounds__(256) void stats_out(const float* __restrict__ H, int total,
                                                 float* __restrict__ sum, float* __restrict__ sumsq) {
    __shared__ float ls[D_OUT], lq[D_OUT];
    if (threadIdx.x < D_OUT) { ls[threadIdx.x] = 0.f; lq[threadIdx.x] = 0.f; }
    __syncthreads();
    int stride = gridDim.x * blockDim.x;
    for (int i = blockIdx.x * blockDim.x + threadIdx.x; i < total; i += stride) {
        float v = H[i];
        int c = i % D_OUT;
        atomicAdd(&ls[c], v);
        atomicAdd(&lq[c], v * v);
    }
    __syncthreads();
    if (threadIdx.x < D_OUT) {
        atomicAdd(&sum[threadIdx.x], ls[threadIdx.x]);
        atomicAdd(&sumsq[threadIdx.x], lq[threadIdx.x]);
    }
}

// ---------------------------------------------------------------- scale/shift from sums: bn(x) = x*scale + shift
__global__ void finalize_stats(const float* __restrict__ sum, const float* __restrict__ sumsq,
                               const float* __restrict__ gamma, const float* __restrict__ beta,
                               int n, float invN, float* __restrict__ scale, float* __restrict__ shift) {
    int c = blockIdx.x * blockDim.x + threadIdx.x;
    if (c < n) {
        float m = sum[c] * invN;
        float var = sumsq[c] * invN - m * m;
        float rstd = rsqrtf(var + BN_EPS);
        float sc = rstd * gamma[c];
        scale[c] = sc;
        shift[c] = beta[c] - m * sc;
    }
}

// ---------------------------------------------------------------- agg2 = relu(bn1(h_pre))   (self term)
__global__ void bn_relu_init(const float* __restrict__ H, const float* __restrict__ scale,
                             const float* __restrict__ shift, float* __restrict__ out, int total4) {
    int stride = gridDim.x * blockDim.x;
    for (int i = blockIdx.x * blockDim.x + threadIdx.x; i < total4; i += stride) {
        float4 v = ((const float4*)H)[i];
        int c = (i & 63) * 4;                   // 256 cols = 64 f4 per row
        float4 o;
        o.x = fmaxf(v.x * scale[c + 0] + shift[c + 0], 0.f);
        o.y = fmaxf(v.y * scale[c + 1] + shift[c + 1], 0.f);
        o.z = fmaxf(v.z * scale[c + 2] + shift[c + 2], 0.f);
        o.w = fmaxf(v.w * scale[c + 3] + shift[c + 3], 0.f);
        ((float4*)out)[i] = o;
    }
}

// ---------------------------------------------------------------- scatter layer 2: agg2[dst] += relu(bn1(h_pre[src]))  (256 feats = 64 f4)
__global__ void scatter2(const float* __restrict__ H, const int* __restrict__ src,
                         const int* __restrict__ dst, const float* __restrict__ scale,
                         const float* __restrict__ shift, float* __restrict__ agg, int E) {
    long long total = (long long)E * 64;
    long long stride = (long long)gridDim.x * blockDim.x;
    for (long long w = blockIdx.x * (long long)blockDim.x + threadIdx.x; w < total; w += stride) {
        int e = (int)(w >> 6);
        int c = (int)(w & 63);
        int s = src[e], d = dst[e];
        float4 v = *(const float4*)(H + (size_t)s * D_HID + c * 4);
        int cc = c * 4;
        float a0 = fmaxf(v.x * scale[cc + 0] + shift[cc + 0], 0.f);
        float a1 = fmaxf(v.y * scale[cc + 1] + shift[cc + 1], 0.f);
        float a2 = fmaxf(v.z * scale[cc + 2] + shift[cc + 2], 0.f);
        float a3 = fmaxf(v.w * scale[cc + 3] + shift[cc + 3], 0.f);
        float* p = agg + (size_t)d * D_HID + cc;
        atomicAdd(p + 0, a0); atomicAdd(p + 1, a1);
        atomicAdd(p + 2, a2); atomicAdd(p + 3, a3);
    }
}

// ---------------------------------------------------------------- GEMM2: h2 = agg2[N,256] @ W2[256,40] + b2
__global__ __launch_bounds__(256) void gemm2(const float* __restrict__ A, const float* __restrict__ W,
                                             const float* __restrict__ bias, float* __restrict__ C, int N) {
    __shared__ float At[64][33];
    __shared__ float Bt[32][D_OUT];
    int r0 = blockIdx.x * 64;
    int tid = threadIdx.x;
    int row = tid & 63;
    int cg  = tid >> 6;          // 0..3, 10 cols each
    float acc[10];
    #pragma unroll
    for (int j = 0; j < 10; ++j) acc[j] = 0.f;

    for (int k0 = 0; k0 < D_HID; k0 += 32) {
        #pragma unroll
        for (int i = 0; i < 2; ++i) {            // A tile 64x32 = 512 f4
            int idx = i * 256 + tid;
            int r = idx >> 3, kk4 = idx & 7;
            float4 v = make_float4(0.f, 0.f, 0.f, 0.f);
            if (r0 + r < N)
                v = *(const float4*)(A + (size_t)(r0 + r) * D_HID + k0 + kk4 * 4);
            At[r][kk4 * 4 + 0] = v.x; At[r][kk4 * 4 + 1] = v.y;
            At[r][kk4 * 4 + 2] = v.z; At[r][kk4 * 4 + 3] = v.w;
        }
        #pragma unroll
        for (int i = 0; i < 5; ++i) {            // B tile 32x40 = 1280 scalars
            int idx = i * 256 + tid;
            int kk = idx / D_OUT, c = idx - kk * D_OUT;
            Bt[kk][c] = W[(size_t)(k0 + kk) * D_OUT + c];
        }
        __syncthreads();
        #pragma unroll
        for (int kk = 0; kk < 32; ++kk) {
            float a = At[row][kk];
            #pragma unroll
            for (int j = 0; j < 10; ++j)
                acc[j] += a * Bt[kk][cg * 10 + j];
        }
        __syncthreads();
    }
    if (r0 + row < N) {
        float* out = C + (size_t)(r0 + row) * D_OUT + cg * 10;
        #pragma unroll
        for (int j = 0; j < 10; ++j)
            out[j] = acc[j] + bias[cg * 10 + j];
    }
}

// ---------------------------------------------------------------- BN2 + log_softmax, LDS-staged, 256 rows/block
__global__ __launch_bounds__(256) void bn_logsoftmax(const float* __restrict__ H, const float* __restrict__ scale,
                                                     const float* __restrict__ shift, float* __restrict__ out, int N) {
    __shared__ float buf[256 * 41];              // row stride 41 -> 2-way conflicts only (free)
    int r0 = blockIdx.x * 256;
    int tid = threadIdx.x;
    int nrow = min(256, N - r0);
    int total = nrow * D_OUT;
    for (int i = tid; i < total; i += 256)
        buf[i + i / D_OUT] = H[(size_t)r0 * D_OUT + i];
    __syncthreads();
    if (tid < nrow) {
        int base = tid * 41;
        float m = -1e30f;
        #pragma unroll
        for (int j = 0; j < D_OUT; ++j) {
            float v = buf[base + j] * scale[j] + shift[j];
            buf[base + j] = v;
            m = fmaxf(m, v);
        }
        float s = 0.f;
        #pragma unroll
        for (int j = 0; j < D_OUT; ++j)
            s += expf(buf[base + j] - m);
        float lse = m + logf(s);
        #pragma unroll
        for (int j = 0; j < D_OUT; ++j)
            buf[base + j] -= lse;
    }
    __syncthreads();
    for (int i = tid; i < total; i += 256)
        out[(size_t)r0 * D_OUT + i] = buf[i + i / D_OUT];
}

// =================================================================
extern "C" void kernel_launch(void* const* d_in, const int* in_sizes, int n_in,
                              void* d_out, int out_size, void* d_ws, size_t ws_size,
                              hipStream_t stream) {
    const float* x      = (const float*)d_in[0];
    const int*   ei     = (const int*)d_in[1];
    const float* W1     = (const float*)d_in[2];
    const float* b1     = (const float*)d_in[3];
    const float* W2     = (const float*)d_in[4];
    const float* b2     = (const float*)d_in[5];
    const float* gamma1 = (const float*)d_in[6];
    const float* beta1  = (const float*)d_in[7];
    const float* gamma2 = (const float*)d_in[8];
    const float* beta2  = (const float*)d_in[9];
    float* out = (float*)d_out;

    const int N = in_sizes[0] / D_IN;      // 50000
    const int E = in_sizes[1] / 2;         // 800000
    const int* src = ei;
    const int* dst = ei + E;

    // ---------------- workspace layout (floats) ----------------
    float* ws = (float*)d_ws;
    size_t off = 0;
    float* agg  = ws + off; off += (size_t)N * D_HID;   // agg1 (first N*100) and agg2 overlay
    float* hpre = ws + off; off += (size_t)N * D_HID;
    float* h2   = ws + off; off += (size_t)N * D_OUT;
    float* stats = ws + off;
    float* colsum1   = stats + 0;     // 256
    float* colsumsq1 = stats + 256;   // 256
    float* colsum2   = stats + 512;   // 40 (padded 64)
    float* colsumsq2 = stats + 576;   // 40 (padded 64)
    float* scale1    = stats + 640;   // 256
    float* shift1    = stats + 896;   // 256
    float* scale2    = stats + 1152;  // 40 (padded 64)
    float* shift2    = stats + 1216;  // 40 (padded 64)

    // zero the accumulators (colsum1..colsumsq2 = 640 floats)
    hipMemsetAsync(stats, 0, 640 * sizeof(float), stream);

    // ---------------- layer 1 ----------------
    init_copy_f4<<<2048, 256, 0, stream>>>(x, agg, N * (D_IN / 4));
    scatter1<<<4096, 256, 0, stream>>>(x, src, dst, agg, E);
    gemm1<<<dim3((N + 63) / 64, D_HID / 64), 256, 0, stream>>>(agg, W1, b1, hpre, N);
    stats_hid<<<512, 256, 0, stream>>>(hpre, N, colsum1, colsumsq1);
    finalize_stats<<<1, 256, 0, stream>>>(colsum1, colsumsq1, gamma1, beta1, D_HID, 1.0f / N, scale1, shift1);

    // ---------------- layer 2 ----------------
    bn_relu_init<<<2048, 256, 0, stream>>>(hpre, scale1, shift1, agg, N * (D_HID / 4));
    scatter2<<<4096, 256, 0, stream>>>(hpre, src, dst, scale1, shift1, agg, E);
    gemm2<<<(N + 63) / 64, 256, 0, stream>>>(agg, W2, b2, h2, N);
    stats_out<<<1024, 256, 0, stream>>>(h2, N * D_OUT, colsum2, colsumsq2);
    finalize_stats<<<1, 64, 0, stream>>>(colsum2, colsumsq2, gamma2, beta2, D_OUT, 1.0f / N, scale2, shift2);

    // ---------------- BN2 + log_softmax ----------------
    bn_logsoftmax<<<(N + 255) / 256, 256, 0, stream>>>(h2, scale2, shift2, out, N);
}

// Round 2
// 596.519 us; speedup vs baseline: 6.8866x; 6.8866x over previous
//
#include <hip/hip_runtime.h>
#include <hip/hip_bf16.h>

#define D_IN   100
#define D_HID  256
#define D_OUT  40
#define BN_EPS 1e-5f

// ---------------------------------------------------------------- CSR build: histogram of dst into cnt (=cursor array)
__global__ void hist_dst(const int* __restrict__ dst, int* __restrict__ cnt, int E) {
    int stride = gridDim.x * blockDim.x;
    for (int i = blockIdx.x * blockDim.x + threadIdx.x; i < E; i += stride)
        atomicAdd(&cnt[dst[i]], 1);
}

// ---------------------------------------------------------------- single-block exclusive scan of counts -> row_ptr, init cursor
__global__ __launch_bounds__(1024) void scan_counts(int* __restrict__ cnt_cursor,
                                                    int* __restrict__ rp, int N) {
    __shared__ int bufA[1024], bufB[1024];
    int tid = threadIdx.x;
    int L = (N + 1023) >> 10;
    int start = min(tid * L, N);
    int end = min(start + L, N);
    int s = 0;
    for (int i = start; i < end; ++i) s += cnt_cursor[i];
    bufA[tid] = s;
    __syncthreads();
    int* in = bufA; int* out = bufB;
    for (int off = 1; off < 1024; off <<= 1) {
        out[tid] = (tid >= off) ? (in[tid - off] + in[tid]) : in[tid];
        __syncthreads();
        int* t = in; in = out; out = t;
    }
    int base = (tid == 0) ? 0 : in[tid - 1];
    for (int i = start; i < end; ++i) {
        int cv = cnt_cursor[i];
        rp[i] = base;
        cnt_cursor[i] = base;      // cursor init for fill pass
        base += cv;
    }
    if (end == N) rp[N] = base;    // tail threads all write the same total
}

// ---------------------------------------------------------------- fill CSR adjacency (order within bucket arbitrary)
__global__ void fill_csr(const int* __restrict__ src, const int* __restrict__ dst,
                         int* __restrict__ cursor, int* __restrict__ csr, int E) {
    int stride = gridDim.x * blockDim.x;
    for (int i = blockIdx.x * blockDim.x + threadIdx.x; i < E; i += stride) {
        int pos = atomicAdd(&cursor[dst[i]], 1);
        csr[pos] = src[i];
    }
}

// ---------------------------------------------------------------- gather-aggregate: out[n] = f(X[n]) + sum_j f(X[csr_j])
// C4 = row length in float4 (25 for [N,100], 64 for [N,256]); BN: f = relu(x*scale+shift), else identity
template<int C4, bool BN>
__global__ __launch_bounds__(256) void gather_rows(const float* __restrict__ X,
        const int* __restrict__ rp, const int* __restrict__ csr,
        const float* __restrict__ scale, const float* __restrict__ shift,
        float* __restrict__ out, int N) {
    int t = blockIdx.x * blockDim.x + threadIdx.x;
    int n = t / C4;
    int c = t - n * C4;
    if (n >= N) return;
    float4 sc, sh;
    if (BN) { sc = ((const float4*)scale)[c]; sh = ((const float4*)shift)[c]; }
    const float4* Xc = (const float4*)X + c;
    float4 v = Xc[(size_t)n * C4];
    float4 acc;
    if (BN) {
        acc.x = fmaxf(v.x * sc.x + sh.x, 0.f);
        acc.y = fmaxf(v.y * sc.y + sh.y, 0.f);
        acc.z = fmaxf(v.z * sc.z + sh.z, 0.f);
        acc.w = fmaxf(v.w * sc.w + sh.w, 0.f);
    } else {
        acc = v;
    }
    int e0 = rp[n], e1 = rp[n + 1];
    for (int e = e0; e < e1; ++e) {
        int s = csr[e];
        float4 u = Xc[(size_t)s * C4];
        if (BN) {
            acc.x += fmaxf(u.x * sc.x + sh.x, 0.f);
            acc.y += fmaxf(u.y * sc.y + sh.y, 0.f);
            acc.z += fmaxf(u.z * sc.z + sh.z, 0.f);
            acc.w += fmaxf(u.w * sc.w + sh.w, 0.f);
        } else {
            acc.x += u.x; acc.y += u.y; acc.z += u.z; acc.w += u.w;
        }
    }
    ((float4*)out)[(size_t)n * C4 + c] = acc;
}

// ---------------------------------------------------------------- GEMM1: h_pre = agg1[N,100] @ W1[100,256] + b1
__global__ __launch_bounds__(256) void gemm1(const float* __restrict__ A, const float* __restrict__ W,
                                             const float* __restrict__ bias, float* __restrict__ C, int N) {
    __shared__ float At[64][33];
    __shared__ float Bt[32][64];
    int r0 = blockIdx.x * 64;
    int c0 = blockIdx.y * 64;
    int tid = threadIdx.x;
    int row = tid & 63;
    int cg  = tid >> 6;
    float acc[16];
    #pragma unroll
    for (int j = 0; j < 16; ++j) acc[j] = 0.f;

    for (int k0 = 0; k0 < D_IN; k0 += 32) {
        #pragma unroll
        for (int i = 0; i < 2; ++i) {
            int idx = i * 256 + tid;
            int r = idx >> 3, kk4 = idx & 7;
            int k = k0 + kk4 * 4;
            float4 v = make_float4(0.f, 0.f, 0.f, 0.f);
            if (r0 + r < N && k < D_IN)
                v = *(const float4*)(A + (size_t)(r0 + r) * D_IN + k);
            At[r][kk4 * 4 + 0] = v.x; At[r][kk4 * 4 + 1] = v.y;
            At[r][kk4 * 4 + 2] = v.z; At[r][kk4 * 4 + 3] = v.w;
        }
        #pragma unroll
        for (int i = 0; i < 2; ++i) {
            int idx = i * 256 + tid;
            int kk = idx >> 4, c4 = idx & 15;
            int k = k0 + kk;
            float4 v = make_float4(0.f, 0.f, 0.f, 0.f);
            if (k < D_IN)
                v = *(const float4*)(W + (size_t)k * D_HID + c0 + c4 * 4);
            Bt[kk][c4 * 4 + 0] = v.x; Bt[kk][c4 * 4 + 1] = v.y;
            Bt[kk][c4 * 4 + 2] = v.z; Bt[kk][c4 * 4 + 3] = v.w;
        }
        __syncthreads();
        #pragma unroll
        for (int kk = 0; kk < 32; ++kk) {
            float a = At[row][kk];
            #pragma unroll
            for (int j = 0; j < 16; ++j)
                acc[j] += a * Bt[kk][cg * 16 + j];
        }
        __syncthreads();
    }
    if (r0 + row < N) {
        float* out = C + (size_t)(r0 + row) * D_HID + c0 + cg * 16;
        #pragma unroll
        for (int j = 0; j < 16; ++j)
            out[j] = acc[j] + bias[c0 + cg * 16 + j];
    }
}

// ---------------------------------------------------------------- column stats for [N,256]
__global__ __launch_bounds__(256) void stats_hid(const float* __restrict__ H, int N,
                                                 float* __restrict__ sum, float* __restrict__ sumsq) {
    int c = threadIdx.x;
    float s = 0.f, q = 0.f;
    for (int r = blockIdx.x; r < N; r += gridDim.x) {
        float v = H[(size_t)r * D_HID + c];
        s += v; q += v * v;
    }
    atomicAdd(&sum[c], s);
    atomicAdd(&sumsq[c], q);
}

// ---------------------------------------------------------------- column stats for [N,40]
__global__ __launch_bounds__(256) void stats_out(const float* __restrict__ H, int total,
                                                 float* __restrict__ sum, float* __restrict__ sumsq) {
    __shared__ float ls[D_OUT], lq[D_OUT];
    if (threadIdx.x < D_OUT) { ls[threadIdx.x] = 0.f; lq[threadIdx.x] = 0.f; }
    __syncthreads();
    int stride = gridDim.x * blockDim.x;
    for (int i = blockIdx.x * blockDim.x + threadIdx.x; i < total; i += stride) {
        float v = H[i];
        int c = i % D_OUT;
        atomicAdd(&ls[c], v);
        atomicAdd(&lq[c], v * v);
    }
    __syncthreads();
    if (threadIdx.x < D_OUT) {
        atomicAdd(&sum[threadIdx.x], ls[threadIdx.x]);
        atomicAdd(&sumsq[threadIdx.x], lq[threadIdx.x]);
    }
}

// ---------------------------------------------------------------- bn(x) = x*scale + shift
__global__ void finalize_stats(const float* __restrict__ sum, const float* __restrict__ sumsq,
                               const float* __restrict__ gamma, const float* __restrict__ beta,
                               int n, float invN, float* __restrict__ scale, float* __restrict__ shift) {
    int c = blockIdx.x * blockDim.x + threadIdx.x;
    if (c < n) {
        float m = sum[c] * invN;
        float var = sumsq[c] * invN - m * m;
        float rstd = rsqrtf(var + BN_EPS);
        float sc = rstd * gamma[c];
        scale[c] = sc;
        shift[c] = beta[c] - m * sc;
    }
}

// ---------------------------------------------------------------- GEMM2: h2 = agg2[N,256] @ W2[256,40] + b2
__global__ __launch_bounds__(256) void gemm2(const float* __restrict__ A, const float* __restrict__ W,
                                             const float* __restrict__ bias, float* __restrict__ C, int N) {
    __shared__ float At[64][33];
    __shared__ float Bt[32][D_OUT];
    int r0 = blockIdx.x * 64;
    int tid = threadIdx.x;
    int row = tid & 63;
    int cg  = tid >> 6;
    float acc[10];
    #pragma unroll
    for (int j = 0; j < 10; ++j) acc[j] = 0.f;

    for (int k0 = 0; k0 < D_HID; k0 += 32) {
        #pragma unroll
        for (int i = 0; i < 2; ++i) {
            int idx = i * 256 + tid;
            int r = idx >> 3, kk4 = idx & 7;
            float4 v = make_float4(0.f, 0.f, 0.f, 0.f);
            if (r0 + r < N)
                v = *(const float4*)(A + (size_t)(r0 + r) * D_HID + k0 + kk4 * 4);
            At[r][kk4 * 4 + 0] = v.x; At[r][kk4 * 4 + 1] = v.y;
            At[r][kk4 * 4 + 2] = v.z; At[r][kk4 * 4 + 3] = v.w;
        }
        #pragma unroll
        for (int i = 0; i < 5; ++i) {
            int idx = i * 256 + tid;
            int kk = idx / D_OUT, c = idx - kk * D_OUT;
            Bt[kk][c] = W[(size_t)(k0 + kk) * D_OUT + c];
        }
        __syncthreads();
        #pragma unroll
        for (int kk = 0; kk < 32; ++kk) {
            float a = At[row][kk];
            #pragma unroll
            for (int j = 0; j < 10; ++j)
                acc[j] += a * Bt[kk][cg * 10 + j];
        }
        __syncthreads();
    }
    if (r0 + row < N) {
        float* out = C + (size_t)(r0 + row) * D_OUT + cg * 10;
        #pragma unroll
        for (int j = 0; j < 10; ++j)
            out[j] = acc[j] + bias[cg * 10 + j];
    }
}

// ---------------------------------------------------------------- BN2 + log_softmax, LDS-staged, 256 rows/block
__global__ __launch_bounds__(256) void bn_logsoftmax(const float* __restrict__ H, const float* __restrict__ scale,
                                                     const float* __restrict__ shift, float* __restrict__ out, int N) {
    __shared__ float buf[256 * 41];
    int r0 = blockIdx.x * 256;
    int tid = threadIdx.x;
    int nrow = min(256, N - r0);
    int total = nrow * D_OUT;
    for (int i = tid; i < total; i += 256)
        buf[i + i / D_OUT] = H[(size_t)r0 * D_OUT + i];
    __syncthreads();
    if (tid < nrow) {
        int base = tid * 41;
        float m = -1e30f;
        #pragma unroll
        for (int j = 0; j < D_OUT; ++j) {
            float v = buf[base + j] * scale[j] + shift[j];
            buf[base + j] = v;
            m = fmaxf(m, v);
        }
        float s = 0.f;
        #pragma unroll
        for (int j = 0; j < D_OUT; ++j)
            s += expf(buf[base + j] - m);
        float lse = m + logf(s);
        #pragma unroll
        for (int j = 0; j < D_OUT; ++j)
            buf[base + j] -= lse;
    }
    __syncthreads();
    for (int i = tid; i < total; i += 256)
        out[(size_t)r0 * D_OUT + i] = buf[i + i / D_OUT];
}

// =================================================================
extern "C" void kernel_launch(void* const* d_in, const int* in_sizes, int n_in,
                              void* d_out, int out_size, void* d_ws, size_t ws_size,
                              hipStream_t stream) {
    const float* x      = (const float*)d_in[0];
    const int*   ei     = (const int*)d_in[1];
    const float* W1     = (const float*)d_in[2];
    const float* b1     = (const float*)d_in[3];
    const float* W2     = (const float*)d_in[4];
    const float* b2     = (const float*)d_in[5];
    const float* gamma1 = (const float*)d_in[6];
    const float* beta1  = (const float*)d_in[7];
    const float* gamma2 = (const float*)d_in[8];
    const float* beta2  = (const float*)d_in[9];
    float* out = (float*)d_out;

    const int N = in_sizes[0] / D_IN;      // 50000
    const int E = in_sizes[1] / 2;         // 800000
    const int* src = ei;
    const int* dst = ei + E;

    // ---------------- workspace layout ----------------
    // reg1   : N*256 floats  (agg1 uses first N*100 as [N,100]; agg2 uses all as [N,256])
    // hpre   : N*256 floats
    // h2     : N*40  floats  -- CSR ints (900001 <= 2000000) overlay here until gemm2
    // stats  : 1280 floats
    float* ws = (float*)d_ws;
    float* reg1 = ws;
    float* hpre = reg1 + (size_t)N * D_HID;
    float* h2   = hpre + (size_t)N * D_HID;
    float* stats = h2 + (size_t)N * D_OUT;
    float* colsum1   = stats + 0;     // 256
    float* colsumsq1 = stats + 256;   // 256
    float* colsum2   = stats + 512;   // 40 (pad 64)
    float* colsumsq2 = stats + 576;   // 40 (pad 64)
    float* scale1    = stats + 640;   // 256
    float* shift1    = stats + 896;   // 256
    float* scale2    = stats + 1152;  // 40 (pad 64)
    float* shift2    = stats + 1216;  // 40 (pad 64)

    int* ibase  = (int*)h2;
    int* rp     = ibase;               // N+1
    int* cursor = ibase + N + 1;       // N (doubles as count array)
    int* csr    = ibase + 2 * N + 1;   // E

    // zero stats accumulators + counts
    hipMemsetAsync(stats, 0, 640 * sizeof(float), stream);
    hipMemsetAsync(cursor, 0, (size_t)N * sizeof(int), stream);

    // ---------------- CSR build (shared by both layers) ----------------
    hist_dst<<<1024, 256, 0, stream>>>(dst, cursor, E);
    scan_counts<<<1, 1024, 0, stream>>>(cursor, rp, N);
    fill_csr<<<1024, 256, 0, stream>>>(src, dst, cursor, csr, E);

    // ---------------- layer 1 ----------------
    gather_rows<25, false><<<(N * 25 + 255) / 256, 256, 0, stream>>>(x, rp, csr, nullptr, nullptr, reg1, N);
    gemm1<<<dim3((N + 63) / 64, D_HID / 64), 256, 0, stream>>>(reg1, W1, b1, hpre, N);
    stats_hid<<<512, 256, 0, stream>>>(hpre, N, colsum1, colsumsq1);
    finalize_stats<<<1, 256, 0, stream>>>(colsum1, colsumsq1, gamma1, beta1, D_HID, 1.0f / N, scale1, shift1);

    // ---------------- layer 2 (BN1+relu fused into gather) ----------------
    gather_rows<64, true><<<(N * 64 + 255) / 256, 256, 0, stream>>>(hpre, rp, csr, scale1, shift1, reg1, N);
    gemm2<<<(N + 63) / 64, 256, 0, stream>>>(reg1, W2, b2, h2, N);   // overwrites CSR region (dead)
    stats_out<<<1024, 256, 0, stream>>>(h2, N * D_OUT, colsum2, colsumsq2);
    finalize_stats<<<1, 64, 0, stream>>>(colsum2, colsumsq2, gamma2, beta2, D_OUT, 1.0f / N, scale2, shift2);

    // ---------------- BN2 + log_softmax ----------------
    bn_logsoftmax<<<(N + 255) / 256, 256, 0, stream>>>(h2, scale2, shift2, out, N);
}